// Round 16
// baseline (48014.722 us; speedup 1.0000x reference)
//
#include <hip/hip_runtime.h>

typedef unsigned short u16;
typedef unsigned int   u32;
typedef __attribute__((ext_vector_type(8))) __bf16 bf16x8;
typedef __attribute__((ext_vector_type(4))) float  f32x4;

#define T_STEPS 256
#define BATCH   512

__device__ __forceinline__ float b2f(u16 u){
  union { u32 i; float f; } v; v.i = ((u32)u) << 16; return v.f;
}
__device__ __forceinline__ u16 f2b(float f){
  u32 x = __float_as_uint(f);
  return (u16)((x + 0x7fffu + ((x >> 16) & 1u)) >> 16);
}
__device__ __forceinline__ float sigm_f(float x){ return 1.f/(1.f + __expf(-x)); }
__device__ __forceinline__ float tanh_f(float x){
  x = fminf(15.f, fmaxf(-15.f, x));
  float e = __expf(2.f*x);
  return (e - 1.f)/(e + 1.f);
}
__device__ __forceinline__ f32x4 MF(bf16x8 a, bf16x8 b, f32x4 c){
  return __builtin_amdgcn_mfma_f32_16x16x32_bf16(a, b, c, 0, 0, 0);
}
__device__ __forceinline__ void dma16(const u16* g, u16* l){
  __builtin_amdgcn_global_load_lds(
      (const __attribute__((address_space(1))) void*)g,
      (__attribute__((address_space(3))) void*)l, 16, 0, 0);
}
// fragment offset (u16 units) of element (col = m*16+cl, row) inside a
// 4-frag [kc][lane][8] column-slice block of a 128-wide tensor
__device__ __forceinline__ int fragoff(int m, int cl, int row){
  int ko = ((m & 1) << 4) | cl;
  return ((m >> 1) * 512) + (((((ko >> 3) << 4) | row)) * 8) + (ko & 7);
}
// offset for a 512-wide tensor (att): acol in [0,512)
__device__ __forceinline__ int aoff(int acol, int row){
  int ko = acol & 31;
  return ((acol >> 5) * 512) + (((((ko >> 3) << 4) | row)) * 8) + (ko & 7);
}

// ---- packers (verified round 9) ----
__global__ void pack_w(const float* __restrict__ src, u16* __restrict__ dst,
                       int Ksrc, int N, int ktOff, int KT)
{
  int i = blockIdx.x*256 + threadIdx.x;
  if (i >= Ksrc*N) return;
  int j = i & 7, l = (i >> 3) & 63, p = i >> 9;
  int nkt = Ksrc >> 5;
  int kt = p % nkt, nt = p / nkt;
  int k = (kt << 5) + ((l >> 4) << 3) + j;
  int n = (nt << 4) + (l & 15);
  dst[(((nt*KT + ktOff + kt) << 6) + l)*8 + j] = f2b(src[(size_t)k*N + n]);
}

__global__ void pack_bias(const float* Wb, const float* Ub, const float* Vb,
                          const float* a1, const float* a2,
                          const float* e10, const float* e20,
                          const float* e11, const float* e21, float* bout)
{
  int i = blockIdx.x*256 + threadIdx.x;
  if (i >= 2688) return;
  float v;
  if      (i < 512)  v = Wb[i];
  else if (i < 1024) { int n = i - 512; v = Wb[n] + Ub[n] + Vb[n]; }
  else if (i < 1152) v = a1[i - 1024];
  else if (i < 2176) v = a2[i - 1152];
  else if (i < 2304) v = e10[i - 2176];
  else if (i < 2432) v = e20[i - 2304];
  else if (i < 2560) v = e11[i - 2432];
  else               v = e21[i - 2560];
  bout[i] = v;
}

__global__ void zero_flags(u32* f){ if (threadIdx.x < 256) f[threadIdx.x] = 0; }

#define RELEASE(fp) do{ __threadfence(); __syncthreads(); \
  if (tid == 0) __hip_atomic_fetch_add((fp), 1u, __ATOMIC_RELEASE, __HIP_MEMORY_SCOPE_AGENT); \
}while(0)
#define SPIN(fp, tgt) do{ if (tid == 0){ \
    while (budget > 0 && \
           __hip_atomic_load((fp), __ATOMIC_ACQUIRE, __HIP_MEMORY_SCOPE_AGENT) < (u32)(tgt)){ \
      --budget; __builtin_amdgcn_s_sleep(1); } } \
  __syncthreads(); \
}while(0)

// 256 blocks (32 clusters x 8 members) x 256 threads; weights LDS-resident.
__global__ __launch_bounds__(256, 1) void marn_clu(
  const float* __restrict__ eeg, const float* __restrict__ eog,
  const u16* __restrict__ UVWt, const u16* __restrict__ A1t,
  const u16* __restrict__ A2t,  const u16* __restrict__ D10t,
  const u16* __restrict__ D20t, const u16* __restrict__ D11t,
  const u16* __restrict__ D21t, const float* __restrict__ bias,
  u32* __restrict__ flags, u16* __restrict__ comm,
  float* __restrict__ out)
{
  __shared__ u16  wlds[128*512];   // 128 KB member weight slice, [frag][lane][8]
  __shared__ float gS[2048];       // 8 KB gate staging [mod][gate][row][16]
  __shared__ float uac[4][64][4];  // 4 KB S3a partial accs

  const int tid = threadIdx.x;
  const int w = tid >> 6, l = tid & 63;
  const int hi = l >> 4, li = l & 15;
  const int c = blockIdx.x >> 3, m = blockIdx.x & 7;
  const int r0 = c * 16;
  int budget = 1 << 22;            // spin-poll budget: deadlock -> fast wrong answer

  u16* CB = comm + (size_t)c * 65536;   // 128 KB per cluster (u16 units)
  u16* Hb = CB;                          // [slot][mod][4][512]  16 KB
  u16* Yb = CB + 8192;                   // [slot][4][512]        8 KB
  u16* Ab = CB + 12288;                  // [slot][mod][16][512] 64 KB
  u16* Ub = CB + 45056;                  // [slot][mod][4][512]  16 KB
  u16* Zb = CB + 53248;                  // [slot][mod][4][512]  16 KB
  u32* flg = flags + c * 8;

  // ---- preload member weight slice into LDS (once) ----
  for (int f = w; f < 128; f += 4){
    const u16* src;
    if      (f < 48){ int wv = f/12, kc = f%12; src = UVWt + (size_t)((m+8*wv)*12 + kc)*512; }
    else if (f < 56){ int kc = f-48;            src = A1t  + (size_t)(m*8 + kc)*512; }
    else if (f < 88){ int q = f-56; int sp = q>>2, kc = q&3; int s2 = sp>>1, p = sp&1;
                      src = A2t + (size_t)((m + 8*p + 16*s2)*4 + kc)*512; }
    else if (f < 104){ int kc = f-88;  src = D10t + (size_t)(m*16 + kc)*512; }
    else if (f < 120){ int kc = f-104; src = D11t + (size_t)(m*16 + kc)*512; }
    else if (f < 124){ int kc = f-120; src = D20t + (size_t)(m*4 + kc)*512; }
    else             { int kc = f-124; src = D21t + (size_t)(m*4 + kc)*512; }
    dma16(src + l*8, wlds + f*512);
  }
  asm volatile("s_waitcnt vmcnt(0)" ::: "memory");
  __syncthreads();

  // ---- per-thread bias registers ----
  const int colm = m*16 + li;
  const int ccl = tid & 15, crow = (tid >> 4) & 15;   // S1ep cell (row,col)
  const int ccol = m*16 + ccl;
  float cbW[4], cbA[4];
  #pragma unroll
  for (int q = 0; q < 4; ++q){ cbW[q] = bias[q*128 + ccol]; cbA[q] = bias[512 + q*128 + ccol]; }
  const float a1b  = bias[1024 + colm];
  const int  gcol  = ((m + 8*(w & 1))*16 + li);       // S2b g (valid for w<2)
  float ab[4];
  #pragma unroll
  for (int q = 0; q < 4; ++q) ab[q] = bias[1152 + q*256 + gcol];
  const float e1b0 = bias[2176 + colm], e1b1 = bias[2432 + colm];
  const float e2b0 = bias[2304 + colm], e2b1 = bias[2560 + colm];
  float cc0 = 0.f, cc1 = 0.f;                          // c-state per cell

  for (int t = 0; t < T_STEPS; ++t){
    const int s = t & 1, s1 = s ^ 1;

    // ===== S1: gate slice (all 4 waves; wave w -> gate w, nt = m+8w) =====
    if (t > 0) SPIN(flg + 4, 8*t);     // z(t-1) gathered
    {
      const float* xs0 = eeg + ((size_t)t*BATCH + r0 + (l & 15))*128 + hi*8;
      const float* xs1 = eog + ((size_t)t*BATCH + r0 + (l & 15))*128 + hi*8;
      f32x4 acc0 = {0,0,0,0}, acc1 = {0,0,0,0};
      #pragma unroll
      for (int kc = 0; kc < 4; ++kc){
        union { u16 u[8]; bf16x8 v; } x0, x1;
        f32x4 p0 = *(const f32x4*)(xs0 + kc*32);
        f32x4 p1 = *(const f32x4*)(xs0 + kc*32 + 4);
        f32x4 q0 = *(const f32x4*)(xs1 + kc*32);
        f32x4 q1 = *(const f32x4*)(xs1 + kc*32 + 4);
        #pragma unroll
        for (int j = 0; j < 4; ++j){
          x0.u[j] = f2b(p0[j]); x0.u[4+j] = f2b(p1[j]);
          x1.u[j] = f2b(q0[j]); x1.u[4+j] = f2b(q1[j]);
        }
        bf16x8 bfr = *(const bf16x8*)(wlds + (w*12 + kc)*512 + l*8);
        acc0 = MF(x0.v, bfr, acc0);
        acc1 = MF(x1.v, bfr, acc1);
      }
      if (t > 0){
        #pragma unroll
        for (int kc = 0; kc < 4; ++kc){
          bf16x8 h0 = *(const bf16x8*)(Hb + s1*4096 +        kc*512 + l*8);
          bf16x8 h1 = *(const bf16x8*)(Hb + s1*4096 + 2048 + kc*512 + l*8);
          bf16x8 bfr = *(const bf16x8*)(wlds + (w*12 + 4 + kc)*512 + l*8);
          acc0 = MF(h0, bfr, acc0);
          acc1 = MF(h1, bfr, acc1);
        }
        #pragma unroll
        for (int kc = 0; kc < 4; ++kc){
          bf16x8 z0 = *(const bf16x8*)(Zb + s1*4096 +        kc*512 + l*8);
          bf16x8 z1 = *(const bf16x8*)(Zb + s1*4096 + 2048 + kc*512 + l*8);
          bf16x8 bfr = *(const bf16x8*)(wlds + (w*12 + 8 + kc)*512 + l*8);
          acc0 = MF(z0, bfr, acc0);
          acc1 = MF(z1, bfr, acc1);
        }
      }
      #pragma unroll
      for (int jr = 0; jr < 4; ++jr){
        int row = hi*4 + jr;
        gS[((0*4 + w)*16 + row)*16 + li] = acc0[jr];
        gS[((1*4 + w)*16 + row)*16 + li] = acc1[jr];
      }
    }
    __syncthreads();
    // S1ep: cell update (thread -> (crow, ccl), mods 0 and 1)
    {
      float bb0 = (t == 0 ? cbW[0] : cbA[0]), bb1 = (t == 0 ? cbW[1] : cbA[1]);
      float bb2 = (t == 0 ? cbW[2] : cbA[2]), bb3 = (t == 0 ? cbW[3] : cbA[3]);
      int fo = fragoff(m, ccl, crow);
      {
        float f  = sigm_f(gS[((0*4+0)*16 + crow)*16 + ccl] + bb0);
        float ii = sigm_f(gS[((0*4+1)*16 + crow)*16 + ccl] + bb1);
        float o  = sigm_f(gS[((0*4+2)*16 + crow)*16 + ccl] + bb2);
        float ch = tanh_f(gS[((0*4+3)*16 + crow)*16 + ccl] + bb3);
        cc0 = f*cc0 + ii*ch;
        __builtin_nontemporal_store(f2b(tanh_f(cc0)*o), Hb + s*4096 + fo);
      }
      {
        float f  = sigm_f(gS[((1*4+0)*16 + crow)*16 + ccl] + bb0);
        float ii = sigm_f(gS[((1*4+1)*16 + crow)*16 + ccl] + bb1);
        float o  = sigm_f(gS[((1*4+2)*16 + crow)*16 + ccl] + bb2);
        float ch = tanh_f(gS[((1*4+3)*16 + crow)*16 + ccl] + bb3);
        cc1 = f*cc1 + ii*ch;
        __builtin_nontemporal_store(f2b(tanh_f(cc1)*o), Hb + s*4096 + 2048 + fo);
      }
    }
    RELEASE(flg + 0);

    // ===== S2a: y slice (wave 0) =====
    SPIN(flg + 0, 8*(t+1));
    if (w == 0){
      f32x4 acc = {0,0,0,0};
      #pragma unroll
      for (int kc = 0; kc < 4; ++kc)
        acc = MF(*(const bf16x8*)(Hb + s*4096 + kc*512 + l*8),
                 *(const bf16x8*)(wlds + (48 + kc)*512 + l*8), acc);
      #pragma unroll
      for (int kc = 0; kc < 4; ++kc)
        acc = MF(*(const bf16x8*)(Hb + s*4096 + 2048 + kc*512 + l*8),
                 *(const bf16x8*)(wlds + (52 + kc)*512 + l*8), acc);
      #pragma unroll
      for (int jr = 0; jr < 4; ++jr){
        int row = hi*4 + jr;
        __builtin_nontemporal_store(f2b(tanh_f(acc[jr] + a1b)),
                                    Yb + s*2048 + fragoff(m, li, row));
      }
    }
    RELEASE(flg + 1);

    // ===== S2b: logits + softmax + att slices (waves 0,1) =====
    SPIN(flg + 1, 8*(t+1));
    if (w < 2){
      float h0v[4], h1v[4];
      #pragma unroll
      for (int jr = 0; jr < 4; ++jr){
        int fo = fragoff(m, li, hi*4 + jr);
        h0v[jr] = b2f(Hb[s*4096 + fo]);
        h1v[jr] = b2f(Hb[s*4096 + 2048 + fo]);
      }
      bf16x8 yf[4];
      #pragma unroll
      for (int kc = 0; kc < 4; ++kc)
        yf[kc] = *(const bf16x8*)(Yb + s*2048 + kc*512 + l*8);
      f32x4 q[4] = {{0,0,0,0},{0,0,0,0},{0,0,0,0},{0,0,0,0}};
      #pragma unroll
      for (int st = 0; st < 4; ++st)
        #pragma unroll
        for (int kc = 0; kc < 4; ++kc)
          q[st] = MF(yf[kc], *(const bf16x8*)(wlds + (56 + (st*2 + w)*4 + kc)*512 + l*8), q[st]);
      const int g = gcol;
      #pragma unroll
      for (int jr = 0; jr < 4; ++jr){
        int row = hi*4 + jr;
        float v0 = q[0][jr] + ab[0], v1 = q[1][jr] + ab[1];
        float v2 = q[2][jr] + ab[2], v3 = q[3][jr] + ab[3];
        float mx = fmaxf(fmaxf(v0,v1), fmaxf(v2,v3));
        float e0 = __expf(v0-mx), e1 = __expf(v1-mx);
        float e2 = __expf(v2-mx), e3 = __expf(v3-mx);
        float inv = 1.f/(e0+e1+e2+e3);
        __builtin_nontemporal_store(f2b(e0*inv*h0v[jr]), Ab + s*16384 +        aoff(g,       row));
        __builtin_nontemporal_store(f2b(e1*inv*h0v[jr]), Ab + s*16384 +        aoff(256 + g, row));
        __builtin_nontemporal_store(f2b(e2*inv*h1v[jr]), Ab + s*16384 + 8192 + aoff(g,       row));
        __builtin_nontemporal_store(f2b(e3*inv*h1v[jr]), Ab + s*16384 + 8192 + aoff(256 + g, row));
      }
    }
    RELEASE(flg + 2);

    // ===== S3a: u slice (4 waves: mod = w&1, K-half = w>>1) =====
    SPIN(flg + 2, 8*(t+1));
    {
      const int mod = w & 1, half = w >> 1;
      f32x4 acc = {0,0,0,0};
      #pragma unroll
      for (int k8 = 0; k8 < 8; ++k8){
        int kc = half*8 + k8;
        acc = MF(*(const bf16x8*)(Ab + s*16384 + mod*8192 + kc*512 + l*8),
                 *(const bf16x8*)(wlds + (88 + mod*16 + kc)*512 + l*8), acc);
      }
      #pragma unroll
      for (int r = 0; r < 4; ++r) uac[w][l][r] = acc[r];
    }
    __syncthreads();
    if (w < 2){
      const int mod = w;
      #pragma unroll
      for (int jr = 0; jr < 4; ++jr){
        int row = hi*4 + jr;
        float u = uac[mod][l][jr] + uac[mod+2][l][jr] + (mod ? e1b1 : e1b0);
        __builtin_nontemporal_store(f2b(tanh_f(u)),
                                    Ub + s*4096 + mod*2048 + fragoff(m, li, row));
      }
    }
    RELEASE(flg + 3);

    // ===== S3b: z slice + output (waves 0,1) =====
    SPIN(flg + 3, 8*(t+1));
    if (w < 2){
      const int mod = w;
      f32x4 acc = {0,0,0,0};
      #pragma unroll
      for (int kc = 0; kc < 4; ++kc)
        acc = MF(*(const bf16x8*)(Ub + s*4096 + mod*2048 + kc*512 + l*8),
                 *(const bf16x8*)(wlds + (120 + mod*4 + kc)*512 + l*8), acc);
      #pragma unroll
      for (int jr = 0; jr < 4; ++jr){
        int row = hi*4 + jr;
        float z = acc[jr] + (mod ? e2b1 : e2b0);
        __builtin_nontemporal_store(z, &out[((size_t)t*BATCH + r0 + row)*256 + mod*128 + colm]);
        __builtin_nontemporal_store(f2b(z), Zb + s*4096 + mod*2048 + fragoff(m, li, row));
      }
    }
    RELEASE(flg + 4);
  }
}

extern "C" void kernel_launch(void* const* d_in, const int* in_sizes, int n_in,
                              void* d_out, int out_size, void* d_ws, size_t ws_size,
                              hipStream_t stream)
{
  const float* eeg = (const float*)d_in[0];
  const float* eog = (const float*)d_in[1];
  const float* Ww  = (const float*)d_in[2];
  const float* Wb  = (const float*)d_in[3];
  const float* Uw  = (const float*)d_in[4];
  const float* Ub  = (const float*)d_in[5];
  const float* Vw  = (const float*)d_in[6];
  const float* Vb  = (const float*)d_in[7];
  const float* A1  = (const float*)d_in[8];
  const float* a1  = (const float*)d_in[9];
  const float* A2  = (const float*)d_in[10];
  const float* a2  = (const float*)d_in[11];
  const float* D10 = (const float*)d_in[12];
  const float* e10 = (const float*)d_in[13];
  const float* D20 = (const float*)d_in[14];
  const float* e20 = (const float*)d_in[15];
  const float* D11 = (const float*)d_in[16];
  const float* e11 = (const float*)d_in[17];
  const float* D21 = (const float*)d_in[18];
  const float* e21 = (const float*)d_in[19];

  char* ws = (char*)d_ws;
  u16*  UVWt = (u16*)(ws);                  // 393216 B
  u16*  A1t  = (u16*)(ws + 393216);         // 65536 B
  u16*  A2t  = (u16*)(ws + 458752);         // 262144 B
  u16*  D10t = (u16*)(ws + 720896);         // 131072 B
  u16*  D20t = (u16*)(ws + 851968);         // 32768 B
  u16*  D11t = (u16*)(ws + 884736);         // 131072 B
  u16*  D21t = (u16*)(ws + 1015808);        // 32768 B
  float* bias = (float*)(ws + 1048576);     // 10752 B
  u32*  flags = (u32*)(ws + 1064960);       // 1024 B
  u16*  comm  = (u16*)(ws + 1114112);       // 32 clusters x 128 KB = 4 MB

  auto nb = [](int n){ return dim3((unsigned)((n + 255)/256)); };
  pack_w<<<nb(65536),  256, 0, stream>>>(Ww,  UVWt, 128, 512,  0, 12);
  pack_w<<<nb(65536),  256, 0, stream>>>(Uw,  UVWt, 128, 512,  4, 12);
  pack_w<<<nb(65536),  256, 0, stream>>>(Vw,  UVWt, 128, 512,  8, 12);
  pack_w<<<nb(32768),  256, 0, stream>>>(A1,  A1t,  256, 128,  0, 8);
  pack_w<<<nb(131072), 256, 0, stream>>>(A2,  A2t,  128, 1024, 0, 4);
  pack_w<<<nb(65536),  256, 0, stream>>>(D10, D10t, 512, 128,  0, 16);
  pack_w<<<nb(16384),  256, 0, stream>>>(D20, D20t, 128, 128,  0, 4);
  pack_w<<<nb(65536),  256, 0, stream>>>(D11, D11t, 512, 128,  0, 16);
  pack_w<<<nb(16384),  256, 0, stream>>>(D21, D21t, 128, 128,  0, 4);
  pack_bias<<<nb(2688), 256, 0, stream>>>(Wb, Ub, Vb, a1, a2, e10, e20, e11, e21, bias);
  zero_flags<<<1, 256, 0, stream>>>(flags);

  marn_clu<<<256, 256, 0, stream>>>(eeg, eog, UVWt, A1t, A2t,
                                    D10t, D20t, D11t, D21t, bias,
                                    flags, comm, (float*)d_out);
}

// Round 18
// 6229.422 us; speedup vs baseline: 7.7077x; 7.7077x over previous
//
#include <hip/hip_runtime.h>

typedef unsigned short u16;
typedef unsigned int   u32;
typedef __attribute__((ext_vector_type(8))) __bf16 bf16x8;
typedef __attribute__((ext_vector_type(4))) float  f32x4;

#define T_STEPS 256
#define BATCH   512
#define RB      16
#define NBLK    32

#define WAITV(N) asm volatile("s_waitcnt vmcnt(" #N ")" ::: "memory")
#define LGKM0    asm volatile("s_waitcnt lgkmcnt(0)" ::: "memory")

__device__ __forceinline__ float b2f(u16 u){
  union { u32 i; float f; } v; v.i = ((u32)u) << 16; return v.f;
}
__device__ __forceinline__ u16 f2b(float f){
  u32 x = __float_as_uint(f);
  return (u16)((x + 0x7fffu + ((x >> 16) & 1u)) >> 16);
}
__device__ __forceinline__ float sigm_f(float x){ return 1.f/(1.f + __expf(-x)); }
__device__ __forceinline__ float tanh_f(float x){
  x = fminf(15.f, fmaxf(-15.f, x));
  float e = __expf(2.f*x);
  return (e - 1.f)/(e + 1.f);
}
__device__ __forceinline__ f32x4 MF(bf16x8 a, bf16x8 b, f32x4 c){
  return __builtin_amdgcn_mfma_f32_16x16x32_bf16(a, b, c, 0, 0, 0);
}
// lgkm-only barrier: LDS visibility; vmem (DMA weight stream) rides across.
__device__ __forceinline__ void BAR(){
  asm volatile("s_waitcnt lgkmcnt(0)" ::: "memory");
  __builtin_amdgcn_s_barrier();
}
// compile-time-folded counted vmcnt wait
__device__ __forceinline__ void waitv_n(int n){
  if      (n == 0) WAITV(0);
  else if (n == 2) WAITV(2);
  else if (n == 4) WAITV(4);
  else             WAITV(6);
}
// async global->LDS DMA, 16B/lane; LDS dest = uniform base + lane*16
__device__ __forceinline__ void dma16(const u16* g, u16* l){
  __builtin_amdgcn_global_load_lds(
      (const __attribute__((address_space(1))) void*)g,
      (__attribute__((address_space(3))) void*)l, 16, 0, 0);
}

// MFMA 16x16x32 bf16 lane maps (HW-verified m89)
__device__ __forceinline__ bf16x8 frA(const u16* buf, int l, int kc, int RS){
  int r = l & 15;
  int byte = r*RS + kc*64 + ((l >> 4) << 4);
  byte ^= (r & 7) << 4;
  return *(const bf16x8*)((const char*)buf + byte);
}
__device__ __forceinline__ void st16(u16* buf, int r, int c, u16 v, int RS){
  int byte = r*RS + c*2; byte ^= (r & 7) << 4;
  *(u16*)((char*)buf + byte) = v;
}
__device__ __forceinline__ float ld16f(const u16* buf, int r, int c, int RS){
  int byte = r*RS + c*2; byte ^= (r & 7) << 4;
  return b2f(*(const u16*)((const char*)buf + byte));
}
__device__ __forceinline__ void st16x4(u16* buf, int r, int c, ushort4 v, int RS){
  int byte = r*RS + c*2; byte ^= (r & 7) << 4;
  *(ushort4*)((char*)buf + byte) = v;
}

// step-invariant fragment source list F0..F127 (1KB frag-packed units)
__device__ __forceinline__ const u16* fsrc(int f, int w,
  const u16* UVWt, const u16* A1t, const u16* A2t,
  const u16* D10t, const u16* D11t, const u16* D20t, const u16* D21t)
{
  if (f < 48){ int kc = f >> 2, g = f & 3; return UVWt + (size_t)((w + 8*g)*12 + kc)*512; }
  if (f < 56){ return A1t + (size_t)(w*8 + (f - 48))*512; }
  if (f < 88){ int j = (f - 56) >> 2, kc = f & 3;
               int nt = (j < 4) ? (w + 16*j) : (w + 8 + 16*(j - 4));
               return A2t + (size_t)(nt*4 + kc)*512; }
  if (f < 104){ return D10t + (size_t)(w*16 + (f - 88))*512; }
  if (f < 120){ return D11t + (size_t)(w*16 + (f - 104))*512; }
  if (f < 124){ return D20t + (size_t)(w*4 + (f - 120))*512; }
  return D21t + (size_t)(w*4 + (f - 124))*512;
}

// f32 src -> bf16 fragment-packed dst (verified round 9)
__global__ void pack_w(const float* __restrict__ src, u16* __restrict__ dst,
                       int Ksrc, int N, int ktOff, int KT)
{
  int i = blockIdx.x*256 + threadIdx.x;
  if (i >= Ksrc*N) return;
  int j = i & 7, l = (i >> 3) & 63, p = i >> 9;
  int nkt = Ksrc >> 5;
  int kt = p % nkt, nt = p / nkt;
  int k = (kt << 5) + ((l >> 4) << 3) + j;
  int n = (nt << 4) + (l & 15);
  dst[(((nt*KT + ktOff + kt) << 6) + l)*8 + j] = f2b(src[(size_t)k*N + n]);
}

__global__ void pack_bias(const float* Wb, const float* Ub, const float* Vb,
                          const float* a1, const float* a2,
                          const float* e10, const float* e20,
                          const float* e11, const float* e21, float* bout)
{
  int i = blockIdx.x*256 + threadIdx.x;
  if (i >= 2688) return;
  float v;
  if      (i < 512)  v = Wb[i];
  else if (i < 1024) { int n = i - 512; v = Wb[n] + Ub[n] + Vb[n]; }
  else if (i < 1152) v = a1[i - 1024];
  else if (i < 2176) v = a2[i - 1152];
  else if (i < 2304) v = e10[i - 2176];
  else if (i < 2432) v = e20[i - 2304];
  else if (i < 2560) v = e11[i - 2432];
  else               v = e21[i - 2560];
  bout[i] = v;
}

// 32 blocks x 512 threads (8 waves). Pair-granular depth-8 DMA weight
// pipeline; WAR-protected (LGKM0 before any slot re-issue); counted vmcnt.
__global__ __launch_bounds__(512, 2) void marn_pipe2(
  const float* __restrict__ eeg, const float* __restrict__ eog,
  const u16* __restrict__ UVWt, const u16* __restrict__ A1t,
  const u16* __restrict__ A2t,  const u16* __restrict__ D10t,
  const u16* __restrict__ D20t, const u16* __restrict__ D11t,
  const u16* __restrict__ D21t, const float* __restrict__ bias,
  float* __restrict__ out)
{
  __shared__ u16 aS1[2][16*384];   // [x|h|z] per mod, RS=768  (24 KB)
  __shared__ u16 aS2b[16*128];     // y, RS=256                ( 4 KB)
  __shared__ u16 aS3a[2][16*512];  // att per mod, RS=1024     (32 KB)
  __shared__ u16 aS3b[2][16*128];  // u per mod, RS=256        ( 8 KB)
  __shared__ u16 ring[8][4096];    // 8 waves x 8 slots x 1KB  (64 KB)

  const int tid = threadIdx.x;
  const int w = tid >> 6, l = tid & 63;
  const int hi = l >> 4, li = l & 15;
  const int r0 = blockIdx.x * RB;
  u16* ringW = &ring[w][0];

#define ISSUE1(ff) do{ const int fi_ = (ff) & 127; \
  dma16(fsrc(fi_, w, UVWt,A1t,A2t,D10t,D11t,D20t,D21t) + l*8, \
        ringW + (fi_ & 7)*512); }while(0)
#define ISS2(pp) do{ ISSUE1(2*(pp)); ISSUE1(2*(pp)+1); }while(0)
#define RDF(f) (*(const bf16x8*)(ringW + ((f) & 7)*512 + l*8))

  for (int i = tid; i < 2*16*384; i += 512) ((u16*)aS1)[i] = 0;  // h,z zero
  float cst[2][4] = {{0,0,0,0},{0,0,0,0}};

  // per-thread bias registers
  const int col = w*16 + li;
  const int g1c = (w + 8)*16 + li;
  float bW[4], bA[4], a2b0[4], a2b1[4];
  #pragma unroll
  for (int q = 0; q < 4; ++q){
    bW[q]   = bias[q*128 + col];
    bA[q]   = bias[512 + q*128 + col];
    a2b0[q] = bias[1152 + q*256 + col];
    a2b1[q] = bias[1152 + q*256 + g1c];
  }
  const float a1b  = bias[1024 + col];
  const float e1b0 = bias[2176 + col], e1b1 = bias[2432 + col];
  const float e2b0 = bias[2304 + col], e2b1 = bias[2560 + col];

  // x(0) prefetch: 8 u16 per thread (2 float4)
  const int xi = tid << 3;
  const int xm = xi >> 11, xrr = (xi >> 7) & 15, xc = xi & 127;
  const float* xsrc = (xm ? eog : eeg) + ((size_t)(r0 + xrr))*128 + xc;
  f32x4 xa = __builtin_nontemporal_load((const f32x4*)xsrc);
  f32x4 xb = __builtin_nontemporal_load((const f32x4*)(xsrc + 4));
  __syncthreads();                 // init visible before x-stage
  {
    ushort4 va, vb;
    va.x = f2b(xa[0]); va.y = f2b(xa[1]); va.z = f2b(xa[2]); va.w = f2b(xa[3]);
    vb.x = f2b(xb[0]); vb.y = f2b(xb[1]); vb.z = f2b(xb[2]); vb.w = f2b(xb[3]);
    st16x4(&aS1[xm][0], xrr, xc,     va, 768);
    st16x4(&aS1[xm][0], xrr, xc + 4, vb, 768);
  }
  __syncthreads();                 // x(0) staged

  // DMA prologue: pairs 0,1,2 (frags 0..5)
  ISS2(0); ISS2(1); ISS2(2);

  for (int t = 0; t < T_STEPS; ++t){
    // ===== S1: gates GEMM, pairs 0..23 (frags 0..47) =====
    f32x4 ac0[4] = {{0,0,0,0},{0,0,0,0},{0,0,0,0},{0,0,0,0}};
    f32x4 ac1[4] = {{0,0,0,0},{0,0,0,0},{0,0,0,0},{0,0,0,0}};
    #pragma unroll
    for (int kc = 0; kc < 12; ++kc){
      // pair 2kc: frags 4kc, 4kc+1
      WAITV(4);
      ISS2(2*kc + 3);
      bf16x8 fa0 = frA(&aS1[0][0], l, kc, 768);
      bf16x8 fa1 = frA(&aS1[1][0], l, kc, 768);
      {
        bf16x8 b0 = RDF(4*kc), b1 = RDF(4*kc + 1);
        ac0[0] = MF(fa0, b0, ac0[0]);  ac1[0] = MF(fa1, b0, ac1[0]);
        ac0[1] = MF(fa0, b1, ac0[1]);  ac1[1] = MF(fa1, b1, ac1[1]);
      }
      LGKM0;
      // pair 2kc+1: frags 4kc+2, 4kc+3
      WAITV(4);
      ISS2(2*kc + 4);
      {
        bf16x8 b2 = RDF(4*kc + 2), b3 = RDF(4*kc + 3);
        ac0[2] = MF(fa0, b2, ac0[2]);  ac1[2] = MF(fa1, b2, ac1[2]);
        ac0[3] = MF(fa0, b3, ac0[3]);  ac1[3] = MF(fa1, b3, ac1[3]);
      }
      LGKM0;
    }
    BAR();                                        // B1

    // ---- S1ep: in-register LSTHM cell update ----
    {
      #pragma unroll
      for (int jr = 0; jr < 4; ++jr){
        const int row = hi*4 + jr;
        {
          float f  = sigm_f(ac0[0][jr] + (t==0 ? bW[0] : bA[0]));
          float ii = sigm_f(ac0[1][jr] + (t==0 ? bW[1] : bA[1]));
          float o  = sigm_f(ac0[2][jr] + (t==0 ? bW[2] : bA[2]));
          float ch = tanh_f(ac0[3][jr] + (t==0 ? bW[3] : bA[3]));
          cst[0][jr] = f*cst[0][jr] + ii*ch;
          st16(&aS1[0][0], row, 128 + col, f2b(tanh_f(cst[0][jr])*o), 768);
        }
        {
          float f  = sigm_f(ac1[0][jr] + (t==0 ? bW[0] : bA[0]));
          float ii = sigm_f(ac1[1][jr] + (t==0 ? bW[1] : bA[1]));
          float o  = sigm_f(ac1[2][jr] + (t==0 ? bW[2] : bA[2]));
          float ch = tanh_f(ac1[3][jr] + (t==0 ? bW[3] : bA[3]));
          cst[1][jr] = f*cst[1][jr] + ii*ch;
          st16(&aS1[1][0], row, 128 + col, f2b(tanh_f(cst[1][jr])*o), 768);
        }
      }
    }
    BAR();                                        // B2

    // ===== S2a: y = tanh([h0|h1]@A1 + a1), pairs 24..27 (frags 48..55) =====
    {
      f32x4 accA = {0,0,0,0};
      #pragma unroll
      for (int p2 = 0; p2 < 4; ++p2){
        const int kcA = 2*p2, kcB = 2*p2 + 1;     // A1 frag indices 0..7
        WAITV(4);
        ISS2(27 + p2);
        bf16x8 aA = (kcA < 4) ? frA(&aS1[0][0], l, 4 + kcA, 768)
                              : frA(&aS1[1][0], l, kcA, 768);
        bf16x8 aB = (kcB < 4) ? frA(&aS1[0][0], l, 4 + kcB, 768)
                              : frA(&aS1[1][0], l, kcB, 768);
        accA = MF(aA, RDF(48 + kcA), accA);
        accA = MF(aB, RDF(48 + kcB), accA);
        LGKM0;
      }
      #pragma unroll
      for (int jr = 0; jr < 4; ++jr)
        st16(aS2b, hi*4 + jr, col, f2b(tanh_f(accA[jr] + a1b)), 256);
    }
    BAR();                                        // B3

    // ===== S2b: logits, pairs 28..43 (frags 56..87); softmax; att =====
    {
      bf16x8 yf[4];
      #pragma unroll
      for (int kc = 0; kc < 4; ++kc) yf[kc] = frA(aS2b, l, kc, 256);
      f32x4 qq[8];
      #pragma unroll
      for (int s = 0; s < 8; ++s) qq[s] = (f32x4){0,0,0,0};
      #pragma unroll
      for (int j = 0; j < 8; ++j){
        const int fb = 56 + 4*j;
        WAITV(4);
        ISS2(31 + 2*j);
        qq[j] = MF(yf[0], RDF(fb),     qq[j]);
        qq[j] = MF(yf[1], RDF(fb + 1), qq[j]);
        LGKM0;
        WAITV(4);
        ISS2(32 + 2*j);
        qq[j] = MF(yf[2], RDF(fb + 2), qq[j]);
        qq[j] = MF(yf[3], RDF(fb + 3), qq[j]);
        LGKM0;
      }
      #pragma unroll
      for (int gq = 0; gq < 2; ++gq){
        const int g = (w + 8*gq)*16 + li;
        const float* ab = gq ? a2b1 : a2b0;
        #pragma unroll
        for (int jr = 0; jr < 4; ++jr){
          const int row = hi*4 + jr;
          float v0 = qq[4*gq + 0][jr] + ab[0];
          float v1 = qq[4*gq + 1][jr] + ab[1];
          float v2 = qq[4*gq + 2][jr] + ab[2];
          float v3 = qq[4*gq + 3][jr] + ab[3];
          float mx = fmaxf(fmaxf(v0,v1), fmaxf(v2,v3));
          float e0 = __expf(v0-mx), e1 = __expf(v1-mx);
          float e2 = __expf(v2-mx), e3 = __expf(v3-mx);
          float inv = 1.f/(e0+e1+e2+e3);
          float h0v = ld16f(&aS1[0][0], row, 128 + (g & 127), 768);
          float h1v = ld16f(&aS1[1][0], row, 128 + (g & 127), 768);
          st16(&aS3a[0][0], row, g,       f2b(e0*inv*h0v), 1024);
          st16(&aS3a[0][0], row, 256 + g, f2b(e1*inv*h0v), 1024);
          st16(&aS3a[1][0], row, g,       f2b(e2*inv*h1v), 1024);
          st16(&aS3a[1][0], row, 256 + g, f2b(e3*inv*h1v), 1024);
        }
      }
    }
    BAR();                                        // B4

    // ===== S3a: u = tanh(att@D1 + e1), pairs 44..59 (frags 88..119) =====
    {
      f32x4 au0 = {0,0,0,0}, au1 = {0,0,0,0};
      #pragma unroll
      for (int j = 0; j < 8; ++j){
        const u16* asrc = (j < 4) ? &aS3a[0][0] : &aS3a[1][0];
        const int fb = 88 + 4*j;
        const int pa = 44 + 2*j, pb = 45 + 2*j;
        // pair pa: frags fb, fb+1
        waitv_n((pa >= 52 && pa <= 54) ? 6 : 4);
        ISS2(pa + 3);
        {
          bf16x8 a0 = frA(asrc, l, (j & 3)*4 + 0, 1024);
          bf16x8 a1 = frA(asrc, l, (j & 3)*4 + 1, 1024);
          if (j < 4){ au0 = MF(a0, RDF(fb), au0);   au0 = MF(a1, RDF(fb+1), au0); }
          else      { au1 = MF(a0, RDF(fb), au1);   au1 = MF(a1, RDF(fb+1), au1); }
        }
        LGKM0;
        // pair pb: frags fb+2, fb+3
        waitv_n((pb >= 52 && pb <= 54) ? 6 : 4);
        ISS2(pb + 3);
        {
          bf16x8 a2 = frA(asrc, l, (j & 3)*4 + 2, 1024);
          bf16x8 a3 = frA(asrc, l, (j & 3)*4 + 3, 1024);
          if (j < 4){ au0 = MF(a2, RDF(fb+2), au0); au0 = MF(a3, RDF(fb+3), au0); }
          else      { au1 = MF(a2, RDF(fb+2), au1); au1 = MF(a3, RDF(fb+3), au1); }
        }
        LGKM0;
        if (pb == 51){   // x(t+1) prefetch, after ISS2(54)
          int tn = (t + 1 < T_STEPS) ? t + 1 : t;
          xa = __builtin_nontemporal_load((const f32x4*)(xsrc + (size_t)tn*BATCH*128));
          xb = __builtin_nontemporal_load((const f32x4*)(xsrc + (size_t)tn*BATCH*128 + 4));
        }
      }
      #pragma unroll
      for (int jr = 0; jr < 4; ++jr){
        st16(&aS3b[0][0], hi*4 + jr, col, f2b(tanh_f(au0[jr] + e1b0)), 256);
        st16(&aS3b[1][0], hi*4 + jr, col, f2b(tanh_f(au1[jr] + e1b1)), 256);
      }
    }
    BAR();                                        // B5

    // ===== S3b: z, pairs 60..63 (frags 120..127); out; feedback =====
    {
      f32x4 az0 = {0,0,0,0}, az1 = {0,0,0,0};
      // pair 60
      WAITV(4);
      ISS2(63);
      az0 = MF(frA(&aS3b[0][0], l, 0, 256), RDF(120), az0);
      az0 = MF(frA(&aS3b[0][0], l, 1, 256), RDF(121), az0);
      LGKM0;
      // pair 61 (its issue, pair 0', deferred)
      WAITV(4);
      az0 = MF(frA(&aS3b[0][0], l, 2, 256), RDF(122), az0);
      az0 = MF(frA(&aS3b[0][0], l, 3, 256), RDF(123), az0);
      LGKM0;
      // pair 62 (issue deferred)
      WAITV(2);
      az1 = MF(frA(&aS3b[1][0], l, 0, 256), RDF(124), az1);
      az1 = MF(frA(&aS3b[1][0], l, 1, 256), RDF(125), az1);
      LGKM0;
      // pair 63 (issue deferred)
      WAITV(0);
      az1 = MF(frA(&aS3b[1][0], l, 2, 256), RDF(126), az1);
      az1 = MF(frA(&aS3b[1][0], l, 3, 256), RDF(127), az1);
      LGKM0;
      // z feedback (LDS) + outputs (NT stores)
      #pragma unroll
      for (int jr = 0; jr < 4; ++jr){
        const int row = hi*4 + jr;
        float z0 = az0[jr] + e2b0;
        float z1 = az1[jr] + e2b1;
        st16(&aS1[0][0], row, 256 + col, f2b(z0), 768);
        st16(&aS1[1][0], row, 256 + col, f2b(z1), 768);
        __builtin_nontemporal_store(z0, &out[((size_t)t*BATCH + r0 + row)*256 + col]);
        __builtin_nontemporal_store(z1, &out[((size_t)t*BATCH + r0 + row)*256 + 128 + col]);
      }
    }
    // stage x(t+1)
    {
      ushort4 va, vb;
      va.x = f2b(xa[0]); va.y = f2b(xa[1]); va.z = f2b(xa[2]); va.w = f2b(xa[3]);
      vb.x = f2b(xb[0]); vb.y = f2b(xb[1]); vb.z = f2b(xb[2]); vb.w = f2b(xb[3]);
      st16x4(&aS1[xm][0], xrr, xc,     va, 768);
      st16x4(&aS1[xm][0], xrr, xc + 4, vb, 768);
    }
    // deferred issues: pairs 0,1,2 of next step (WAR-safe: slots drained above)
    ISS2(0); ISS2(1); ISS2(2);
    BAR();                                        // B6
  }
#undef ISSUE1
#undef ISS2
#undef RDF
}

extern "C" void kernel_launch(void* const* d_in, const int* in_sizes, int n_in,
                              void* d_out, int out_size, void* d_ws, size_t ws_size,
                              hipStream_t stream)
{
  const float* eeg = (const float*)d_in[0];
  const float* eog = (const float*)d_in[1];
  const float* Ww  = (const float*)d_in[2];
  const float* Wb  = (const float*)d_in[3];
  const float* Uw  = (const float*)d_in[4];
  const float* Ub  = (const float*)d_in[5];
  const float* Vw  = (const float*)d_in[6];
  const float* Vb  = (const float*)d_in[7];
  const float* A1  = (const float*)d_in[8];
  const float* a1  = (const float*)d_in[9];
  const float* A2  = (const float*)d_in[10];
  const float* a2  = (const float*)d_in[11];
  const float* D10 = (const float*)d_in[12];
  const float* e10 = (const float*)d_in[13];
  const float* D20 = (const float*)d_in[14];
  const float* e20 = (const float*)d_in[15];
  const float* D11 = (const float*)d_in[16];
  const float* e11 = (const float*)d_in[17];
  const float* D21 = (const float*)d_in[18];
  const float* e21 = (const float*)d_in[19];

  char* ws = (char*)d_ws;
  u16*  UVWt = (u16*)(ws);                  // 393216 B
  u16*  A1t  = (u16*)(ws + 393216);         // 65536 B
  u16*  A2t  = (u16*)(ws + 458752);         // 262144 B
  u16*  D10t = (u16*)(ws + 720896);         // 131072 B
  u16*  D20t = (u16*)(ws + 851968);         // 32768 B
  u16*  D11t = (u16*)(ws + 884736);         // 131072 B
  u16*  D21t = (u16*)(ws + 1015808);        // 32768 B
  float* bias = (float*)(ws + 1048576);     // 2688 f32

  auto nb = [](int n){ return dim3((unsigned)((n + 255)/256)); };
  pack_w<<<nb(65536),  256, 0, stream>>>(Ww,  UVWt, 128, 512,  0, 12);
  pack_w<<<nb(65536),  256, 0, stream>>>(Uw,  UVWt, 128, 512,  4, 12);
  pack_w<<<nb(65536),  256, 0, stream>>>(Vw,  UVWt, 128, 512,  8, 12);
  pack_w<<<nb(32768),  256, 0, stream>>>(A1,  A1t,  256, 128,  0, 8);
  pack_w<<<nb(131072), 256, 0, stream>>>(A2,  A2t,  128, 1024, 0, 4);
  pack_w<<<nb(65536),  256, 0, stream>>>(D10, D10t, 512, 128,  0, 16);
  pack_w<<<nb(16384),  256, 0, stream>>>(D20, D20t, 128, 128,  0, 4);
  pack_w<<<nb(65536),  256, 0, stream>>>(D11, D11t, 512, 128,  0, 16);
  pack_w<<<nb(16384),  256, 0, stream>>>(D21, D21t, 128, 128,  0, 4);
  pack_bias<<<nb(2688), 256, 0, stream>>>(Wb, Ub, Vb, a1, a2, e10, e20, e11, e21, bias);

  marn_pipe2<<<NBLK, 512, 0, stream>>>(eeg, eog, UVWt, A1t, A2t,
                                       D10t, D20t, D11t, D21t, bias, (float*)d_out);
}